// Round 18
// baseline (62.281 us; speedup 1.0000x reference)
//
#include <hip/hip_runtime.h>
#include <hip/hip_bf16.h>
#include <math.h>

typedef short short8 __attribute__((ext_vector_type(8)));
typedef float f32x16 __attribute__((ext_vector_type(16)));

#define BB 16
#define CC 256
#define HH 64
#define WW 64
#define HWX 4096
#define DD 4
#define KD 9
#define KK 81
#define NSLOT 10

// LDS visibility barrier WITHOUT vmcnt drain (global loads/stores stay in flight)
#define RAW_BAR() do { \
    asm volatile("s_waitcnt lgkmcnt(0)" ::: "memory"); \
    __builtin_amdgcn_s_barrier(); \
} while (0)

__device__ __forceinline__ short bf16c(float x) {
    __hip_bfloat16 h = __float2bfloat16(x);
    return *reinterpret_cast<short*>(&h);
}

// 512B-row layout, 5-bit XOR swizzle (R11-measured: 0 conflicts)
__device__ __forceinline__ int lds_byte(int w, int c) {
    return (w * 512 + c * 2) ^ ((w & 31) << 4);
}

// 16 strided loads: c = c0..c0+15 at w=l (row, c0 wave-uniform)
__device__ __forceinline__ void b_issue16(const float* __restrict__ row,
                                          int c0, int l, float* v) {
    #pragma unroll
    for (int j = 0; j < 16; ++j)
        v[j] = row[(size_t)(c0 + j) * HWX + l];
}

// cvt + 2 swizzled ds_write_b128; returns sumsq partial
__device__ __forceinline__ float b_commit16(const float* v, unsigned short* bufp,
                                            int c0, int l) {
    float ss = 0.f;
    #pragma unroll
    for (int j = 0; j < 16; ++j) ss += v[j] * v[j];
    #pragma unroll
    for (int h = 0; h < 2; ++h) {
        short8 st;
        #pragma unroll
        for (int j = 0; j < 8; ++j) st[j] = bf16c(v[h * 8 + j]);
        *(short8*)((char*)bufp + lds_byte(l, c0 + h * 8)) = st;
    }
    return ss;
}

__global__ __launch_bounds__(512) void corr_mfma(
    const float* __restrict__ fA, const float* __restrict__ fB,
    float* __restrict__ out)
{
    // SINGLE 32 KB buffer: total LDS ~37.4 KB (R3's proven multi-block size)
    __shared__ __attribute__((aligned(16))) unsigned short buf[WW * CC]; // 32 KB
    __shared__ float part[2][8 * WW];   // 4 KB ([1] also A partials)
    __shared__ float invA_ls[2][WW];    // 0.5 KB

    const int bid = blockIdx.x;                       // 512 blocks
    const int swzb = (bid & 7) * 64 + (bid >> 3);     // XCD-bijective (512%8==0)
    const int b = swzb >> 5, jr = swzb & 31;
    const int h0 = 2 * jr;

    const int tid = threadIdx.x;
    const int l = tid & 63;
    const int wvu = __builtin_amdgcn_readfirstlane(tid >> 6);  // wave id -> SGPR
    const int g = wvu >> 2;               // group: row h0+g   (uniform)
    const int q = wvu & 3;                // quadrant wave     (uniform)
    const int hg = h0 + g;
    const int ti = q >> 1, tj = q & 1;
    const int ml = l & 31, kg = l >> 5;
    const int m = ti * 32 + ml;           // A row (w)
    const int n = tj * 32 + ml;           // B row (w')

    // ---- A prologue: two rounds through the single buf ----
    short8 afr[16];
    #pragma unroll
    for (int t = 0; t < 2; ++t) {
        {   // stage row h0+t: each of 8 waves covers 32 channels
            const float* Ar = fA + (size_t)b * CC * HWX + (size_t)(h0 + t) * WW;
            float ss = 0.f;
            #pragma unroll
            for (int r2 = 0; r2 < 4; ++r2) {
                const int c = wvu * 32 + r2 * 8;       // uniform
                float v[8]; short8 st;
                #pragma unroll
                for (int j = 0; j < 8; ++j) v[j] = Ar[(size_t)(c + j) * HWX + l];
                #pragma unroll
                for (int j = 0; j < 8; ++j) ss += v[j] * v[j];
                #pragma unroll
                for (int j = 0; j < 8; ++j) st[j] = bf16c(v[j]);
                *(short8*)((char*)buf + lds_byte(l, c)) = st;
            }
            part[1][wvu * 64 + l] = ss;
        }
        __syncthreads();                               // row t staged
        if (tid < WW) {
            float s = 0.f;
            #pragma unroll
            for (int qq = 0; qq < 8; ++qq) s += part[1][qq * 64 + tid];
            invA_ls[t][tid] = 1.f / fmaxf(sqrtf(s), 1e-12f);
        }
        if (g == t) {                                  // hoist this group's frags
            #pragma unroll
            for (int s = 0; s < 16; ++s)
                afr[s] = *(const short8*)((const char*)buf + lds_byte(m, s * 16 + kg * 8));
        }
        __syncthreads();                               // hoist + invA done
        if (g == t) {                                  // fold invA (register-only)
            const float iam = invA_ls[t][m];
            #pragma unroll
            for (int s = 0; s < 16; ++s) {
                short8 tt = afr[s];
                #pragma unroll
                for (int j = 0; j < 8; ++j) {
                    union { unsigned u; float f; } uu;
                    uu.u = ((unsigned)(unsigned short)tt[j]) << 16;
                    tt[j] = bf16c(uu.f * iam);
                }
                afr[s] = tt;
            }
        }
    }

    // ---- slot-0 B staging into buf ----
    const float* fBb = fB + (size_t)b * CC * HWX;
    {
        const int hb0 = h0 - DD;
        if ((unsigned)hb0 < HH) {
            const float* row = fBb + (size_t)hb0 * WW;
            float v[16];
            b_issue16(row, wvu * 32, l, v);
            float ss = b_commit16(v, buf, wvu * 32, l);
            b_issue16(row, wvu * 32 + 16, l, v);
            ss += b_commit16(v, buf, wvu * 32 + 16, l);
            part[0][wvu * 64 + l] = ss;
        }
    }
    __syncthreads();                                   // slot 0 ready

    // ---- slot loop: compute from single buf; commit between two raw barriers ----
    for (int r = 0; r < NSLOT; ++r) {
        const int hb = h0 - DD + r;
        const bool vcur = (unsigned)hb < HH;
        const bool vnext = (r + 1 < NSLOT) && ((unsigned)(hb + 1) < HH);
        const int dy = r - g;
        const bool dyv = (dy >= 0 && dy < KD);
        const bool comp = dyv && vcur;
        const float* nrow = fBb + (size_t)(hb + 1) * WW;
        float* ob = out + (((size_t)b * KK + dy * KD) * HH + hg) * WW;

        // 1. issue ALL next-row loads (fly across the whole compute phase)
        float va[16], vb[16];
        if (vnext) {
            b_issue16(nrow, wvu * 32, l, va);
            b_issue16(nrow, wvu * 32 + 16, l, vb);
        }

        // 2. compute current row from buf
        if (comp) {
            f32x16 acc;
            #pragma unroll
            for (int i = 0; i < 16; ++i) acc[i] = 0.f;
            __builtin_amdgcn_s_setprio(1);
            #pragma unroll
            for (int s = 0; s < 16; ++s) {
                short8 bfr = *(const short8*)((const char*)buf + lds_byte(n, s * 16 + kg * 8));
                acc = __builtin_amdgcn_mfma_f32_32x32x16_bf16(afr[s], bfr, acc, 0, 0, 0);
            }
            __builtin_amdgcn_s_setprio(0);
            float sB = 0.f;
            #pragma unroll
            for (int qq = 0; qq < 8; ++qq) sB += part[r & 1][qq * 64 + n];
            const float ibn = 1.f / fmaxf(sqrtf(sB), 1e-12f);
            #pragma unroll
            for (int rr = 0; rr < 16; ++rr) {
                // D layout (m74/m101): col = lane&31 (=w'), row = (rr&3)+8*(rr>>2)+4*kg
                const int w = ti * 32 + (rr & 3) + 8 * (rr >> 2) + 4 * kg;
                const int dx = n - w + 4;
                if (dx >= 0 && dx < KD)
                    ob[(size_t)dx * HWX + w] = acc[rr] * ibn;   // invA folded in afr
            }
            if (q == 3) {      // zero the 20 pad-corner entries of this plane
                int i = -1;
                if (l < 10) i = l;
                else if (l >= 16 && l < 26) i = l - 16;
                if (i >= 0) {
                    const int wz0 = (i < 4) ? 0 : (i < 7) ? 1 : (i < 9) ? 2 : 3;
                    const int dx0 = i - ((wz0 == 0) ? 0 : (wz0 == 1) ? 4 : (wz0 == 2) ? 7 : 9);
                    const int wz = (l < 10) ? wz0 : 63 - wz0;
                    const int dxz = (l < 10) ? dx0 : 8 - dx0;
                    ob[(size_t)dxz * HWX + wz] = 0.f;
                }
            }
        } else if (dyv) {
            // whole dy-plane is zero padding; out is poisoned so must write
            for (int i = q * 64 + l; i < KD * WW; i += 256)
                ob[(size_t)(i >> 6) * HWX + (i & 63)] = 0.f;
        }

        RAW_BAR();                                     // all buf reads complete
        // 3. commit staged row into the (now free) single buf
        if (vnext) {
            float ssn = b_commit16(va, buf, wvu * 32, l);
            ssn += b_commit16(vb, buf, wvu * 32 + 16, l);
            part[(r + 1) & 1][wvu * 64 + l] = ssn;
        }
        RAW_BAR();                                     // buf + part visible
    }
}

extern "C" void kernel_launch(void* const* d_in, const int* in_sizes, int n_in,
                              void* d_out, int out_size, void* d_ws, size_t ws_size,
                              hipStream_t stream) {
    const float* fA = (const float*)d_in[0];
    const float* fB = (const float*)d_in[1];
    float* outp = (float*)d_out;
    corr_mfma<<<dim3(BB * HH / 2), 512, 0, stream>>>(fA, fB, outp);
}